// Round 13
// baseline (382.931 us; speedup 1.0000x reference)
//
#include <hip/hip_runtime.h>
#include <stdint.h>

#define N_NODES 100000
#define N_EDGES 800000
#define HIDDIM 512
#define HEADS 8
#define FDIM 64

typedef __attribute__((ext_vector_type(4))) float f32x4;
typedef __attribute__((ext_vector_type(8))) short short8;
typedef __attribute__((ext_vector_type(8))) unsigned short ushort8;

// ---- workspace layout (bytes); total need = 113,731,528 ----
static constexpr size_t OFF_PROJ   = 0;            // N*512*2   = 102,400,000 (bf16 proj)
static constexpr size_t OFF_SSRC   = 102400000;    // N*8*4     = 3,200,000
static constexpr size_t OFF_STGT   = 105600000;    // N*8*4
static constexpr size_t OFF_COUNTS = 108800000;    // N*4
static constexpr size_t OFF_CURSOR = 109200000;    // N*4
static constexpr size_t OFF_KEYS   = 109600000;    // 16 (2 uint float-max keys; zero-init = -inf)
static constexpr size_t OFF_ROWOFF = 109600016;    // N*4
static constexpr size_t OFF_SSORT  = 110004112;    // E*4 = 3,200,000 (edge srcs in CSR order)
static constexpr size_t OFF_WB     = 113204112;    // 512*512*2 = 524,288 (bf16 W)
static constexpr size_t OFF_DESC   = 113728400;    // 391*8 = 3,128 (lookback-scan descriptors)

__device__ __forceinline__ unsigned short f2bf(float f) {
  unsigned int u = __builtin_bit_cast(unsigned int, f);
  u += 0x7FFFu + ((u >> 16) & 1u);
  return (unsigned short)(u >> 16);
}
__device__ __forceinline__ float bf2f(unsigned short s) {
  unsigned int u = ((unsigned int)s) << 16;
  return __builtin_bit_cast(float, u);
}
// monotonic float<->uint key for atomicMax on floats; key 0 < key(any finite float)
__device__ __forceinline__ unsigned int fkey(float x) {
  unsigned int b = __builtin_bit_cast(unsigned int, x);
  return (b & 0x80000000u) ? ~b : (b | 0x80000000u);
}
__device__ __forceinline__ float fdec(unsigned int k) {
  unsigned int b = (k & 0x80000000u) ? (k & 0x7FFFFFFFu) : ~k;
  return __builtin_bit_cast(float, b);
}
__device__ __forceinline__ void gload_lds16(const void* g, void* l) {
  __builtin_amdgcn_global_load_lds((const __attribute__((address_space(1))) unsigned int*)g,
                                   (__attribute__((address_space(3))) unsigned int*)l, 16, 0, 0);
}

// ---------------- K0: prep = convert W -> bf16 + zero counts/cursor/keys/desc ----------------
__global__ __launch_bounds__(256) void prep(const float* __restrict__ W,
                                            unsigned short* __restrict__ Wb,
                                            unsigned int* __restrict__ zbase,
                                            unsigned int* __restrict__ descz) {
  int i = blockIdx.x * 256 + threadIdx.x;  // 800,000 threads
  if (i < 32768) {  // 32768 x 8 elems = 262144 = 512*512
    const float4 v0 = *(const float4*)&W[(size_t)i * 8];
    const float4 v1 = *(const float4*)&W[(size_t)i * 8 + 4];
    ushort8 u;
    u[0] = f2bf(v0.x); u[1] = f2bf(v0.y); u[2] = f2bf(v0.z); u[3] = f2bf(v0.w);
    u[4] = f2bf(v1.x); u[5] = f2bf(v1.y); u[6] = f2bf(v1.z); u[7] = f2bf(v1.w);
    *(ushort8*)&Wb[(size_t)i * 8] = u;
  }
  if (i < 200004) zbase[i] = 0;  // counts (100k) + cursor (100k) + keys (4) contiguous
  if (i < 782) descz[i] = 0;     // 391 x u64 scan descriptors
}

// ---------------- K1: GEMM proj = X @ W^T (+b_lin) + fused hist/scores/max ----------------
// EXACT round-6/10 structure (measured ~160us, 0 conflicts): 128x256 tile, BK=64,
// 8 waves (2x4). B staged via global_load_lds with pre-swizzled global source
// (rule #21); A reg-staged f32->bf16 with swizzled ds_write_b128; chunk^=(row&7)
// swizzle. 800,768 threads >= E: each thread does ONE edge-histogram atomicAdd at
// entry (hidden in GEMM memory idle). Epilogue: block LDS max-reduce -> 2 atomics/block.
__global__ __launch_bounds__(512) void gemm_proj(
    const float* __restrict__ X, const unsigned short* __restrict__ Wb,
    const float* __restrict__ b_lin, const float* __restrict__ a_src,
    const float* __restrict__ a_tgt, const int* __restrict__ ei,
    int* __restrict__ counts,
    unsigned short* __restrict__ proj, float* __restrict__ s_src,
    float* __restrict__ s_tgt, unsigned int* __restrict__ keys) {
  __shared__ __align__(16) unsigned short Al[128 * 64];
  __shared__ __align__(16) unsigned short Bl[256 * 64];
  __shared__ float red[16];
  const int t = threadIdx.x;
  const int bm = blockIdx.x, bn = blockIdx.y;
  const int lane = t & 63, wid = t >> 6;
  const int wr = wid >> 2, wc = wid & 3;  // 2x4 wave grid

  // fused degree histogram: one edge per thread, overlapped with GEMM staging
  {
    int e = (bn * 782 + bm) * 512 + t;
    if (e < N_EDGES) atomicAdd(&counts[ei[N_EDGES + e]], 1);
  }

  f32x4 acc[4][4] = {};

  // B staging: wave-load ci = wid*4+i covers Bl rows ci*8..ci*8+7 (1 KB linear).
  // Lane l lands at LDS (row = ci*8 + (l>>3), chunk = l&7); fetch global chunk
  // (l&7)^(l>>3) so that LDS[row][c] = global chunk c^(row&7).
  const int brow0 = bn * 256 + wid * 32 + (lane >> 3);
  const int bsrc_c = ((lane & 7) ^ (lane >> 3)) * 8;  // bf16 elems

  for (int kt = 0; kt < 8; ++kt) {
#pragma unroll
    for (int i = 0; i < 4; ++i)
      gload_lds16(&Wb[(size_t)(brow0 + i * 8) * 512 + kt * 64 + bsrc_c],
                  &Bl[(wid * 4 + i) * 512]);
#pragma unroll
    for (int i = 0; i < 2; ++i) {  // A: 128x64, 8 elems/thread/iter
      int idx8 = i * 512 + t;
      int row = idx8 >> 3, ck = idx8 & 7;
      int grow = bm * 128 + row;
      if (grow >= N_NODES) grow = N_NODES - 1;
      const float4 v0 = *(const float4*)&X[(size_t)grow * 512 + kt * 64 + ck * 8];
      const float4 v1 = *(const float4*)&X[(size_t)grow * 512 + kt * 64 + ck * 8 + 4];
      ushort8 u;
      u[0] = f2bf(v0.x); u[1] = f2bf(v0.y); u[2] = f2bf(v0.z); u[3] = f2bf(v0.w);
      u[4] = f2bf(v1.x); u[5] = f2bf(v1.y); u[6] = f2bf(v1.z); u[7] = f2bf(v1.w);
      *(ushort8*)&Al[row * 64 + ((ck ^ (row & 7)) * 8)] = u;
    }
    __syncthreads();
#pragma unroll
    for (int kk = 0; kk < 2; ++kk) {
      short8 af[4], bfr[4];
#pragma unroll
      for (int i = 0; i < 4; ++i) {
        int row = wr * 64 + i * 16 + (lane & 15);
        int ck = (kk * 4 + (lane >> 4)) ^ (row & 7);
        af[i] = *(const short8*)&Al[row * 64 + ck * 8];
      }
#pragma unroll
      for (int j = 0; j < 4; ++j) {
        int row = wc * 64 + j * 16 + (lane & 15);
        int ck = (kk * 4 + (lane >> 4)) ^ (row & 7);
        bfr[j] = *(const short8*)&Bl[row * 64 + ck * 8];
      }
#pragma unroll
      for (int i = 0; i < 4; ++i)
#pragma unroll
        for (int j = 0; j < 4; ++j)
          acc[i][j] = __builtin_amdgcn_mfma_f32_16x16x32_bf16(af[i], bfr[j], acc[i][j], 0, 0, 0);
    }
    __syncthreads();
  }

  // epilogue: add b_lin, store bf16 proj, fused per-head score dots + block max
  const int col_head_base = bn * 256 + wc * 64;  // wave covers exactly one head
  const int h = col_head_base >> 6;
  float asr[4], atg[4], bl[4];
#pragma unroll
  for (int j = 0; j < 4; ++j) {
    int f = j * 16 + (lane & 15);
    asr[j] = a_src[h * FDIM + f];
    atg[j] = a_tgt[h * FDIM + f];
    bl[j] = b_lin[col_head_base + f];
  }
  float wms = -1e30f, wmt = -1e30f;
#pragma unroll
  for (int i = 0; i < 4; ++i) {
#pragma unroll
    for (int r = 0; r < 4; ++r) {
      int grow = bm * 128 + wr * 64 + i * 16 + (lane >> 4) * 4 + r;
      float v[4];
      float ps = 0.f, pt = 0.f;
#pragma unroll
      for (int j = 0; j < 4; ++j) {
        v[j] = acc[i][j][r] + bl[j];
        ps += v[j] * asr[j];
        pt += v[j] * atg[j];
      }
#pragma unroll
      for (int m = 1; m < 16; m <<= 1) {  // reduce over the 16 col-lanes
        ps += __shfl_xor(ps, m);
        pt += __shfl_xor(pt, m);
      }
      wms = fmaxf(wms, ps);  // padded rows duplicate node N-1 -> harmless for max
      wmt = fmaxf(wmt, pt);
      if (grow < N_NODES) {
#pragma unroll
        for (int j = 0; j < 4; ++j)
          proj[(size_t)grow * 512 + col_head_base + j * 16 + (lane & 15)] = f2bf(v[j]);
        if ((lane & 15) == 0) {  // exactly one writer per (node, head) -> plain store
          s_src[grow * HEADS + h] = ps;
          s_tgt[grow * HEADS + h] = pt;
        }
      }
    }
  }
#pragma unroll
  for (int m = 16; m < 64; m <<= 1) {  // finish wave-wide max
    wms = fmaxf(wms, __shfl_xor(wms, m));
    wmt = fmaxf(wmt, __shfl_xor(wmt, m));
  }
  if (lane == 0) { red[wid] = wms; red[8 + wid] = wmt; }
  __syncthreads();
  if (t == 0) {  // block-level reduce -> 2 atomics per block (no single-address tail)
    float ms = red[0], mt = red[8];
#pragma unroll
    for (int i = 1; i < 8; ++i) { ms = fmaxf(ms, red[i]); mt = fmaxf(mt, red[8 + i]); }
    atomicMax(&keys[0], fkey(ms));
    atomicMax(&keys[1], fkey(mt));
  }
}

// ---------------- K2: single-pass exclusive scan (decoupled lookback) ----------------
// desc[b] packs (status<<32 | blocksum): status 0 = empty, 1 = aggregate, 2 = prefix.
// Single 64-bit atomic word -> no separate fencing needed. 391 blocks co-resident
// on 256 CUs -> lookback spin cannot deadlock. Writes FINAL row_off directly.
__global__ __launch_bounds__(256) void scan_csr(const int* __restrict__ counts,
                                                int* __restrict__ row_off,
                                                unsigned long long* __restrict__ desc) {
  __shared__ int sh[256];
  __shared__ int pfx;
  const int t = threadIdx.x, b = blockIdx.x;
  const int i = b * 256 + t;
  int v = (i < N_NODES) ? counts[i] : 0;
  sh[t] = v;
  __syncthreads();
  for (int off = 1; off < 256; off <<= 1) {
    int x = (t >= off) ? sh[t - off] : 0;
    __syncthreads();
    sh[t] += x;
    __syncthreads();
  }
  const int total = sh[255];
  if (t == 0) {
    if (b == 0) {
      atomicExch(&desc[0], (2ULL << 32) | (unsigned int)total);
      pfx = 0;
    } else {
      atomicExch(&desc[b], (1ULL << 32) | (unsigned int)total);
      int run = 0;
      int j = b - 1;
      while (true) {
        unsigned long long d = atomicAdd(&desc[j], 0ULL);  // coherent load
        unsigned int st = (unsigned int)(d >> 32);
        if (st == 0u) continue;  // predecessor not ready yet
        run += (int)(unsigned int)d;
        if (st == 2u) break;  // hit a full prefix
        --j;
      }
      atomicExch(&desc[b], (2ULL << 32) | (unsigned int)(run + total));
      pfx = run;
    }
  }
  __syncthreads();
  if (i < N_NODES) row_off[i] = pfx + sh[t] - v;
}

// ---------------- K3: scatter edge srcs into CSR order ----------------
__global__ void edge_pass2(const int* __restrict__ ei, const int* __restrict__ row_off,
                           int* __restrict__ cursor, int* __restrict__ sorted_src) {
  int e = blockIdx.x * 256 + threadIdx.x;
  if (e >= N_EDGES) return;
  int src = ei[e], trg = ei[N_EDGES + e];
  int pos = row_off[trg] + atomicAdd(&cursor[trg], 1);
  sorted_src[pos] = src;
}

// ---------------- K4: single-pass softmax-weighted aggregation + bias + PReLU ----------------
// One wave per node (4 waves/block). lane -> (head = lane>>3, 8 features).
// Edges in batches of 8 (avg degree = 8) -> 8 independent gather chains in flight.
__global__ __launch_bounds__(256) void aggregate(
    const int* __restrict__ row_off, const int* __restrict__ counts,
    const int* __restrict__ sorted_src, const float* __restrict__ s_src,
    const float* __restrict__ s_tgt, const unsigned int* __restrict__ keys,
    const unsigned short* __restrict__ proj, const float* __restrict__ bias,
    const float* __restrict__ prelu_a, float* __restrict__ out) {
  const int node = blockIdx.x * 4 + (threadIdx.x >> 6);
  if (node >= N_NODES) return;
  const int lane = threadIdx.x & 63;
  const int h = lane >> 3;        // 8 lanes per head
  const int f8 = (lane & 7) * 8;  // 8 consecutive features per lane
  const int start = row_off[node];
  const int deg = counts[node];
  const float st = s_tgt[node * HEADS + h];
  const float M = fmaxf(0.0f, fdec(keys[0]) + fdec(keys[1]));  // same bound as before

  float acc[8] = {};
  float dsum = 0.f;
  for (int jb = 0; jb < deg; jb += 8) {
    const int nb = deg - jb;  // >= 1
    int s[8];
#pragma unroll
    for (int i = 0; i < 8; ++i) s[i] = sorted_src[start + jb + (i < nb ? i : 0)];
    float x[8];
#pragma unroll
    for (int i = 0; i < 8; ++i) x[i] = s_src[s[i] * HEADS + h];
    ushort8 p[8];
#pragma unroll
    for (int i = 0; i < 8; ++i)
      p[i] = *(const ushort8*)&proj[(size_t)s[i] * 512 + h * 64 + f8];
#pragma unroll
    for (int i = 0; i < 8; ++i) {
      if (i < nb) {
        float xx = x[i] + st;
        float l = xx > 0.f ? xx : 0.01f * xx;
        float e = __expf(l - M);
        dsum += e;
#pragma unroll
        for (int k = 0; k < 8; ++k) acc[k] += e * bf2f(p[i][k]);
      }
    }
  }
  const float inv = 1.0f / (dsum + 1e-16f);  // deg==0 -> acc==0 -> out=bias (matches ref)
  const float pa = prelu_a[0];
  const int c = h * 64 + f8;
  float o[8];
#pragma unroll
  for (int k = 0; k < 8; ++k) {
    float v = acc[k] * inv + bias[c + k];
    o[k] = v >= 0.f ? v : pa * v;
  }
  float4* op = (float4*)&out[(size_t)node * 512 + c];
  op[0] = make_float4(o[0], o[1], o[2], o[3]);
  op[1] = make_float4(o[4], o[5], o[6], o[7]);
}

extern "C" void kernel_launch(void* const* d_in, const int* in_sizes, int n_in,
                              void* d_out, int out_size, void* d_ws, size_t ws_size,
                              hipStream_t stream) {
  const float* X = (const float*)d_in[0];
  const int* ei = (const int*)d_in[1];  // harness passes integer inputs as int32
  const float* W = (const float*)d_in[2];
  const float* b_lin = (const float*)d_in[3];
  const float* a_src = (const float*)d_in[4];
  const float* a_tgt = (const float*)d_in[5];
  const float* bias = (const float*)d_in[6];
  const float* prelu_a = (const float*)d_in[7];

  char* ws = (char*)d_ws;
  unsigned short* proj = (unsigned short*)(ws + OFF_PROJ);
  float* s_src = (float*)(ws + OFF_SSRC);
  float* s_tgt = (float*)(ws + OFF_STGT);
  int* counts = (int*)(ws + OFF_COUNTS);
  int* cursor = (int*)(ws + OFF_CURSOR);
  unsigned int* keys = (unsigned int*)(ws + OFF_KEYS);
  int* row_off = (int*)(ws + OFF_ROWOFF);
  int* sorted_src = (int*)(ws + OFF_SSORT);
  unsigned short* Wb = (unsigned short*)(ws + OFF_WB);
  unsigned long long* desc = (unsigned long long*)(ws + OFF_DESC);

  prep<<<3125, 256, 0, stream>>>(W, Wb, (unsigned int*)(ws + OFF_COUNTS),
                                 (unsigned int*)(ws + OFF_DESC));
  gemm_proj<<<dim3(782, 2), 512, 0, stream>>>(X, Wb, b_lin, a_src, a_tgt, ei, counts,
                                              proj, s_src, s_tgt, keys);
  scan_csr<<<391, 256, 0, stream>>>(counts, row_off, desc);
  edge_pass2<<<3125, 256, 0, stream>>>(ei, row_off, cursor, sorted_src);
  aggregate<<<25000, 256, 0, stream>>>(row_off, counts, sorted_src, s_src, s_tgt, keys,
                                       proj, bias, prelu_a, (float*)d_out);
}

// Round 14
// 352.260 us; speedup vs baseline: 1.0871x; 1.0871x over previous
//
#include <hip/hip_runtime.h>
#include <stdint.h>

#define N_NODES 100000
#define N_EDGES 800000
#define HIDDIM 512
#define HEADS 8
#define FDIM 64

typedef __attribute__((ext_vector_type(4))) float f32x4;
typedef __attribute__((ext_vector_type(8))) short short8;
typedef __attribute__((ext_vector_type(8))) unsigned short ushort8;

// ---- workspace layout (bytes); total need = 113,728,400 ----
static constexpr size_t OFF_PROJ   = 0;            // N*512*2   = 102,400,000 (bf16 proj)
static constexpr size_t OFF_SSRC   = 102400000;    // N*8*4     = 3,200,000
static constexpr size_t OFF_STGT   = 105600000;    // N*8*4
static constexpr size_t OFF_COUNTS = 108800000;    // N*4
static constexpr size_t OFF_CURSOR = 109200000;    // N*4
static constexpr size_t OFF_KEYS   = 109600000;    // 16 (2 uint float-max keys; zero-init = -inf)
static constexpr size_t OFF_ROWOFF = 109600016;    // N*4
static constexpr size_t OFF_BSUM   = 110000016;    // 4096
static constexpr size_t OFF_SSORT  = 110004112;    // E*4 = 3,200,000 (edge srcs in CSR order)
static constexpr size_t OFF_WB     = 113204112;    // 512*512*2 = 524,288 (bf16 W)

__device__ __forceinline__ unsigned short f2bf(float f) {
  unsigned int u = __builtin_bit_cast(unsigned int, f);
  u += 0x7FFFu + ((u >> 16) & 1u);
  return (unsigned short)(u >> 16);
}
__device__ __forceinline__ float bf2f(unsigned short s) {
  unsigned int u = ((unsigned int)s) << 16;
  return __builtin_bit_cast(float, u);
}
// monotonic float<->uint key for atomicMax on floats; key 0 < key(any finite float)
__device__ __forceinline__ unsigned int fkey(float x) {
  unsigned int b = __builtin_bit_cast(unsigned int, x);
  return (b & 0x80000000u) ? ~b : (b | 0x80000000u);
}
__device__ __forceinline__ float fdec(unsigned int k) {
  unsigned int b = (k & 0x80000000u) ? (k & 0x7FFFFFFFu) : ~k;
  return __builtin_bit_cast(float, b);
}
__device__ __forceinline__ void gload_lds16(const void* g, void* l) {
  __builtin_amdgcn_global_load_lds((const __attribute__((address_space(1))) unsigned int*)g,
                                   (__attribute__((address_space(3))) unsigned int*)l, 16, 0, 0);
}

// ---------------- K0: prep = convert W -> bf16 + zero counts/cursor/keys ----------------
__global__ __launch_bounds__(256) void prep(const float* __restrict__ W,
                                            unsigned short* __restrict__ Wb,
                                            unsigned int* __restrict__ zbase) {
  int i = blockIdx.x * 256 + threadIdx.x;  // 800,000 threads
  if (i < 32768) {  // 32768 x 8 elems = 262144 = 512*512
    const float4 v0 = *(const float4*)&W[(size_t)i * 8];
    const float4 v1 = *(const float4*)&W[(size_t)i * 8 + 4];
    ushort8 u;
    u[0] = f2bf(v0.x); u[1] = f2bf(v0.y); u[2] = f2bf(v0.z); u[3] = f2bf(v0.w);
    u[4] = f2bf(v1.x); u[5] = f2bf(v1.y); u[6] = f2bf(v1.z); u[7] = f2bf(v1.w);
    *(ushort8*)&Wb[(size_t)i * 8] = u;
  }
  if (i < 200004) zbase[i] = 0;  // counts (100k) + cursor (100k) + keys (4) contiguous
}

// ---------------- K1: GEMM proj = X @ W^T (+b_lin) + fused hist/scores/max ----------------
// EXACT round-6/10 inner structure (measured ~160us, 0 conflicts): 128x256 tile,
// BK=64, 8 waves (2x4). B staged via global_load_lds with pre-swizzled global
// source (rule #21); A reg-staged f32->bf16 with swizzled ds_write_b128.
// NEW: paired-XCD 1-D grid swizzle — id = q*16 + bn*8 + r (bm = q*8+r) puts the
// two blocks sharing X-rows (bn=0/1) exactly 8 dispatch slots apart -> same XCD
// under round-robin -> bn=1's X re-read hits XCD-local L2 instead of L3.
// Fused histogram: one edge per thread at entry. Epilogue: block LDS max-reduce.
__global__ __launch_bounds__(512) void gemm_proj(
    const float* __restrict__ X, const unsigned short* __restrict__ Wb,
    const float* __restrict__ b_lin, const float* __restrict__ a_src,
    const float* __restrict__ a_tgt, const int* __restrict__ ei,
    int* __restrict__ counts,
    unsigned short* __restrict__ proj, float* __restrict__ s_src,
    float* __restrict__ s_tgt, unsigned int* __restrict__ keys) {
  __shared__ __align__(16) unsigned short Al[128 * 64];
  __shared__ __align__(16) unsigned short Bl[256 * 64];
  __shared__ float red[16];
  const int t = threadIdx.x;
  const int id = blockIdx.x;
  const int q = id >> 4, bn = (id >> 3) & 1, r = id & 7;
  const int bm = q * 8 + r;
  const int lane = t & 63, wid = t >> 6;
  const int wr = wid >> 2, wc = wid & 3;  // 2x4 wave grid

  // fused degree histogram: one edge per thread (1568*512 = 802816 >= E)
  {
    int e = id * 512 + t;
    if (e < N_EDGES) atomicAdd(&counts[ei[N_EDGES + e]], 1);
  }
  if (bm >= 782) return;  // 4 tail blocks: histogram only (uniform exit, pre-barrier)

  f32x4 acc[4][4] = {};

  // B staging: wave-load ci = wid*4+i covers Bl rows ci*8..ci*8+7 (1 KB linear).
  // Lane l lands at LDS (row = ci*8 + (l>>3), chunk = l&7); fetch global chunk
  // (l&7)^(l>>3) so that LDS[row][c] = global chunk c^(row&7).
  const int brow0 = bn * 256 + wid * 32 + (lane >> 3);
  const int bsrc_c = ((lane & 7) ^ (lane >> 3)) * 8;  // bf16 elems

  for (int kt = 0; kt < 8; ++kt) {
#pragma unroll
    for (int i = 0; i < 4; ++i)
      gload_lds16(&Wb[(size_t)(brow0 + i * 8) * 512 + kt * 64 + bsrc_c],
                  &Bl[(wid * 4 + i) * 512]);
#pragma unroll
    for (int i = 0; i < 2; ++i) {  // A: 128x64, 8 elems/thread/iter
      int idx8 = i * 512 + t;
      int row = idx8 >> 3, ck = idx8 & 7;
      int grow = bm * 128 + row;
      if (grow >= N_NODES) grow = N_NODES - 1;
      const float4 v0 = *(const float4*)&X[(size_t)grow * 512 + kt * 64 + ck * 8];
      const float4 v1 = *(const float4*)&X[(size_t)grow * 512 + kt * 64 + ck * 8 + 4];
      ushort8 u;
      u[0] = f2bf(v0.x); u[1] = f2bf(v0.y); u[2] = f2bf(v0.z); u[3] = f2bf(v0.w);
      u[4] = f2bf(v1.x); u[5] = f2bf(v1.y); u[6] = f2bf(v1.z); u[7] = f2bf(v1.w);
      *(ushort8*)&Al[row * 64 + ((ck ^ (row & 7)) * 8)] = u;
    }
    __syncthreads();
#pragma unroll
    for (int kk = 0; kk < 2; ++kk) {
      short8 af[4], bfr[4];
#pragma unroll
      for (int i = 0; i < 4; ++i) {
        int row = wr * 64 + i * 16 + (lane & 15);
        int ck = (kk * 4 + (lane >> 4)) ^ (row & 7);
        af[i] = *(const short8*)&Al[row * 64 + ck * 8];
      }
#pragma unroll
      for (int j = 0; j < 4; ++j) {
        int row = wc * 64 + j * 16 + (lane & 15);
        int ck = (kk * 4 + (lane >> 4)) ^ (row & 7);
        bfr[j] = *(const short8*)&Bl[row * 64 + ck * 8];
      }
#pragma unroll
      for (int i = 0; i < 4; ++i)
#pragma unroll
        for (int j = 0; j < 4; ++j)
          acc[i][j] = __builtin_amdgcn_mfma_f32_16x16x32_bf16(af[i], bfr[j], acc[i][j], 0, 0, 0);
    }
    __syncthreads();
  }

  // epilogue: add b_lin, store bf16 proj, fused per-head score dots + block max
  const int col_head_base = bn * 256 + wc * 64;  // wave covers exactly one head
  const int h = col_head_base >> 6;
  float asr[4], atg[4], bl[4];
#pragma unroll
  for (int j = 0; j < 4; ++j) {
    int f = j * 16 + (lane & 15);
    asr[j] = a_src[h * FDIM + f];
    atg[j] = a_tgt[h * FDIM + f];
    bl[j] = b_lin[col_head_base + f];
  }
  float wms = -1e30f, wmt = -1e30f;
#pragma unroll
  for (int i = 0; i < 4; ++i) {
#pragma unroll
    for (int rr = 0; rr < 4; ++rr) {
      int grow = bm * 128 + wr * 64 + i * 16 + (lane >> 4) * 4 + rr;
      float v[4];
      float ps = 0.f, pt = 0.f;
#pragma unroll
      for (int j = 0; j < 4; ++j) {
        v[j] = acc[i][j][rr] + bl[j];
        ps += v[j] * asr[j];
        pt += v[j] * atg[j];
      }
#pragma unroll
      for (int m = 1; m < 16; m <<= 1) {  // reduce over the 16 col-lanes
        ps += __shfl_xor(ps, m);
        pt += __shfl_xor(pt, m);
      }
      wms = fmaxf(wms, ps);  // padded rows duplicate node N-1 -> harmless for max
      wmt = fmaxf(wmt, pt);
      if (grow < N_NODES) {
#pragma unroll
        for (int j = 0; j < 4; ++j)
          proj[(size_t)grow * 512 + col_head_base + j * 16 + (lane & 15)] = f2bf(v[j]);
        if ((lane & 15) == 0) {  // exactly one writer per (node, head) -> plain store
          s_src[grow * HEADS + h] = ps;
          s_tgt[grow * HEADS + h] = pt;
        }
      }
    }
  }
#pragma unroll
  for (int m = 16; m < 64; m <<= 1) {  // finish wave-wide max
    wms = fmaxf(wms, __shfl_xor(wms, m));
    wmt = fmaxf(wmt, __shfl_xor(wmt, m));
  }
  if (lane == 0) { red[wid] = wms; red[8 + wid] = wmt; }
  __syncthreads();
  if (t == 0) {  // block-level reduce -> 2 atomics per block (no single-address tail)
    float ms = red[0], mt = red[8];
#pragma unroll
    for (int i = 1; i < 8; ++i) { ms = fmaxf(ms, red[i]); mt = fmaxf(mt, red[8 + i]); }
    atomicMax(&keys[0], fkey(ms));
    atomicMax(&keys[1], fkey(mt));
  }
}

// ---------------- K2: exclusive scan of counts -> row_off (+ bsum) ----------------
__global__ void scan1(const int* __restrict__ counts, int* __restrict__ row_off,
                      int* __restrict__ bsum) {
  __shared__ int sh[256];
  int t = threadIdx.x, i = blockIdx.x * 256 + t;
  int v = (i < N_NODES) ? counts[i] : 0;
  sh[t] = v;
  __syncthreads();
  for (int off = 1; off < 256; off <<= 1) {
    int x = (t >= off) ? sh[t - off] : 0;
    __syncthreads();
    sh[t] += x;
    __syncthreads();
  }
  if (i < N_NODES) row_off[i] = sh[t] - v;
  if (t == 255) bsum[blockIdx.x] = sh[255];
}
__global__ void scan2(int* __restrict__ bsum, int nb) {
  __shared__ int sh[512];
  int t = threadIdx.x;
  int v = (t < nb) ? bsum[t] : 0;
  sh[t] = v;
  __syncthreads();
  for (int off = 1; off < 512; off <<= 1) {
    int x = (t >= off) ? sh[t - off] : 0;
    __syncthreads();
    sh[t] += x;
    __syncthreads();
  }
  if (t < nb) bsum[t] = sh[t] - v;  // exclusive scan of block sums
}

// ---------------- K3: scatter edge srcs into CSR order (bsum folded in) ----------------
__global__ void edge_pass2(const int* __restrict__ ei, const int* __restrict__ row_off,
                           const int* __restrict__ bsum, int* __restrict__ cursor,
                           int* __restrict__ sorted_src) {
  int e = blockIdx.x * 256 + threadIdx.x;
  if (e >= N_EDGES) return;
  int src = ei[e], trg = ei[N_EDGES + e];
  int pos = row_off[trg] + bsum[trg >> 8] + atomicAdd(&cursor[trg], 1);
  sorted_src[pos] = src;
}

// ---------------- K4: single-pass softmax-weighted aggregation + bias + PReLU ----------------
// One wave per node (4 waves/block). lane -> (head = lane>>3, 8 features).
// Edges in batches of 8 (avg degree = 8) -> 8 independent gather chains in flight.
__global__ __launch_bounds__(256) void aggregate(
    const int* __restrict__ row_off, const int* __restrict__ bsum,
    const int* __restrict__ counts, const int* __restrict__ sorted_src,
    const float* __restrict__ s_src, const float* __restrict__ s_tgt,
    const unsigned int* __restrict__ keys, const unsigned short* __restrict__ proj,
    const float* __restrict__ bias, const float* __restrict__ prelu_a,
    float* __restrict__ out) {
  const int node = blockIdx.x * 4 + (threadIdx.x >> 6);
  if (node >= N_NODES) return;
  const int lane = threadIdx.x & 63;
  const int h = lane >> 3;        // 8 lanes per head
  const int f8 = (lane & 7) * 8;  // 8 consecutive features per lane
  const int start = row_off[node] + bsum[node >> 8];
  const int deg = counts[node];
  const float st = s_tgt[node * HEADS + h];
  const float M = fmaxf(0.0f, fdec(keys[0]) + fdec(keys[1]));  // same bound as before

  float acc[8] = {};
  float dsum = 0.f;
  for (int jb = 0; jb < deg; jb += 8) {
    const int nb = deg - jb;  // >= 1
    int s[8];
#pragma unroll
    for (int i = 0; i < 8; ++i) s[i] = sorted_src[start + jb + (i < nb ? i : 0)];
    float x[8];
#pragma unroll
    for (int i = 0; i < 8; ++i) x[i] = s_src[s[i] * HEADS + h];
    ushort8 p[8];
#pragma unroll
    for (int i = 0; i < 8; ++i)
      p[i] = *(const ushort8*)&proj[(size_t)s[i] * 512 + h * 64 + f8];
#pragma unroll
    for (int i = 0; i < 8; ++i) {
      if (i < nb) {
        float xx = x[i] + st;
        float l = xx > 0.f ? xx : 0.01f * xx;
        float e = __expf(l - M);
        dsum += e;
#pragma unroll
        for (int k = 0; k < 8; ++k) acc[k] += e * bf2f(p[i][k]);
      }
    }
  }
  const float inv = 1.0f / (dsum + 1e-16f);  // deg==0 -> acc==0 -> out=bias (matches ref)
  const float pa = prelu_a[0];
  const int c = h * 64 + f8;
  float o[8];
#pragma unroll
  for (int k = 0; k < 8; ++k) {
    float v = acc[k] * inv + bias[c + k];
    o[k] = v >= 0.f ? v : pa * v;
  }
  float4* op = (float4*)&out[(size_t)node * 512 + c];
  op[0] = make_float4(o[0], o[1], o[2], o[3]);
  op[1] = make_float4(o[4], o[5], o[6], o[7]);
}

extern "C" void kernel_launch(void* const* d_in, const int* in_sizes, int n_in,
                              void* d_out, int out_size, void* d_ws, size_t ws_size,
                              hipStream_t stream) {
  const float* X = (const float*)d_in[0];
  const int* ei = (const int*)d_in[1];  // harness passes integer inputs as int32
  const float* W = (const float*)d_in[2];
  const float* b_lin = (const float*)d_in[3];
  const float* a_src = (const float*)d_in[4];
  const float* a_tgt = (const float*)d_in[5];
  const float* bias = (const float*)d_in[6];
  const float* prelu_a = (const float*)d_in[7];

  char* ws = (char*)d_ws;
  unsigned short* proj = (unsigned short*)(ws + OFF_PROJ);
  float* s_src = (float*)(ws + OFF_SSRC);
  float* s_tgt = (float*)(ws + OFF_STGT);
  int* counts = (int*)(ws + OFF_COUNTS);
  int* cursor = (int*)(ws + OFF_CURSOR);
  unsigned int* keys = (unsigned int*)(ws + OFF_KEYS);
  int* row_off = (int*)(ws + OFF_ROWOFF);
  int* bsum = (int*)(ws + OFF_BSUM);
  int* sorted_src = (int*)(ws + OFF_SSORT);
  unsigned short* Wb = (unsigned short*)(ws + OFF_WB);

  prep<<<3125, 256, 0, stream>>>(W, Wb, (unsigned int*)(ws + OFF_COUNTS));
  gemm_proj<<<1568, 512, 0, stream>>>(X, Wb, b_lin, a_src, a_tgt, ei, counts,
                                      proj, s_src, s_tgt, keys);
  scan1<<<391, 256, 0, stream>>>(counts, row_off, bsum);
  scan2<<<1, 512, 0, stream>>>(bsum, 391);
  edge_pass2<<<3125, 256, 0, stream>>>(ei, row_off, bsum, cursor, sorted_src);
  aggregate<<<25000, 256, 0, stream>>>(row_off, bsum, counts, sorted_src, s_src, s_tgt, keys,
                                       proj, bias, prelu_a, (float*)d_out);
}